// Round 2
// baseline (626.183 us; speedup 1.0000x reference)
//
#include <hip/hip_runtime.h>

#define D 64
#define KC 512        // number of codebook entries
#define EMA_A 0.01f   // 1 - EMA_DECAY
#define CROWS 1024    // rows per histogram block

typedef float v2f __attribute__((ext_vector_type(2)));

// ---- K0: pack emb into pair layout embP[k/2][d][2] + ee[k] = ||emb_k||^2 ----
__global__ __launch_bounds__(256) void k_prep(const float* __restrict__ emb,
                                              float* __restrict__ embP,
                                              float* __restrict__ ee) {
    int k = blockIdx.x * 256 + threadIdx.x;
    if (k >= KC) return;
    float s = 0.f;
#pragma unroll
    for (int d = 0; d < D; ++d) {
        float e = emb[k * D + d];
        s = fmaf(e, e, s);
        embP[(size_t)(k >> 1) * (2 * D) + 2 * d + (k & 1)] = e;
    }
    ee[k] = s;
}

// ---------------- K1: per-row argmin over 512 clusters ----------------
// 1 row/thread (xr[64] stays in VGPRs under the 128-reg cap -> no spills).
// embP pair layout: uniform 8B loads -> SGPR pair -> v_pk_fma_f32 with
// splat-VGPR src. 1024 blocks -> 4 blocks/CU -> ~50% occupancy.
__global__ __launch_bounds__(256, 4) void k_assign(
    const float* __restrict__ x, const float* __restrict__ embP,
    const float* __restrict__ ee, int* __restrict__ idx) {
    int n = blockIdx.x * 256 + threadIdx.x;
    float xr[D];
    const float4* p = (const float4*)(x + (size_t)n * D);
#pragma unroll
    for (int i = 0; i < D / 4; ++i) {
        float4 a = p[i];
        xr[4 * i + 0] = a.x; xr[4 * i + 1] = a.y;
        xr[4 * i + 2] = a.z; xr[4 * i + 3] = a.w;
    }
    float xx = 0.f;
#pragma unroll
    for (int d = 0; d < D; ++d) xx = fmaf(xr[d], xr[d], xx);

    float best = 3.4e38f;
    int bi = 0;
    const v2f* ep = (const v2f*)embP;  // [pair][d] of {k_even, k_odd}
    for (int kp = 0; kp < KC / 2; kp += 4) {  // 4 pairs = 8 clusters per tile
        v2f acc0 = {0.f, 0.f}, acc1 = {0.f, 0.f};
        v2f acc2 = {0.f, 0.f}, acc3 = {0.f, 0.f};
#pragma unroll
        for (int d = 0; d < D; ++d) {
            v2f xd; xd.x = xr[d]; xd.y = xr[d];
            acc0 += xd * ep[(size_t)(kp + 0) * D + d];
            acc1 += xd * ep[(size_t)(kp + 1) * D + d];
            acc2 += xd * ep[(size_t)(kp + 2) * D + d];
            acc3 += xd * ep[(size_t)(kp + 3) * D + d];
        }
        v2f accs[4] = {acc0, acc1, acc2, acc3};
#pragma unroll
        for (int j = 0; j < 4; ++j) {
            int k0 = 2 * (kp + j);
            float d0 = xx - 2.0f * accs[j].x + ee[k0];
            float d1 = xx - 2.0f * accs[j].y + ee[k0 + 1];
            if (d0 < best) { best = d0; bi = k0; }      // strict < keeps
            if (d1 < best) { best = d1; bi = k0 + 1; }  // first-min (jnp.argmin)
        }
    }
    idx[n] = bi;
}

// ---------------- K2a: per-block histogram of cluster counts ----------------
__global__ __launch_bounds__(256) void k_count(const int* __restrict__ idx,
                                               float* __restrict__ gcount, int N) {
    __shared__ int hist[KC];
    int tid = threadIdx.x;
    for (int i = tid; i < KC; i += 256) hist[i] = 0;
    __syncthreads();
    int base = blockIdx.x * CROWS;
    int end = base + CROWS; if (end > N) end = N;
    for (int r = base + tid; r < end; r += 256) atomicAdd(&hist[idx[r]], 1);
    __syncthreads();
    for (int i = tid; i < KC; i += 256)
        gcount[(size_t)blockIdx.x * KC + i] = (float)hist[i];
}

// ---------------- K2b: LDS-privatized segment sums (two k-half passes) -------
// part[] is 64 KB (256 clusters x 64 d). Swizzle (d+k)&63 -> bank (d+k)%32 so
// lanes hitting different clusters spread across banks.
__global__ __launch_bounds__(256) void k_segsum(
    const float* __restrict__ x, const int* __restrict__ idx,
    float* __restrict__ gpart, int N, int P) {
    __shared__ float part[256 * D];  // 64 KB
    int tid = threadIdx.x;
    int chunk = (N + P - 1) / P;
    int base = blockIdx.x * chunk;
    int end = base + chunk; if (end > N) end = N;
    size_t ob = (size_t)blockIdx.x * (KC * D);
    for (int half = 0; half < 2; ++half) {
        for (int i = tid; i < 256 * D; i += 256) part[i] = 0.f;
        __syncthreads();
        for (int r = base + tid; r < end; r += 256) {
            int k = idx[r];
            if ((k >> 8) == half) {
                int kl = k & 255;
                const float4* p = (const float4*)(x + (size_t)r * D);
#pragma unroll
                for (int i = 0; i < D / 4; ++i) {
                    float4 v = p[i];
                    int d = 4 * i;
                    atomicAdd(&part[kl * D + ((d + 0 + kl) & 63)], v.x);
                    atomicAdd(&part[kl * D + ((d + 1 + kl) & 63)], v.y);
                    atomicAdd(&part[kl * D + ((d + 2 + kl) & 63)], v.z);
                    atomicAdd(&part[kl * D + ((d + 3 + kl) & 63)], v.w);
                }
            }
        }
        __syncthreads();
        for (int i = tid; i < 256 * D; i += 256) {
            int kl = i >> 6, d = i & 63;
            gpart[ob + (size_t)half * (256 * D) + i] = part[kl * D + ((d + kl) & 63)];
        }
        __syncthreads();
    }
}

// ---------------- K3a: reduce count partials ----------------
__global__ __launch_bounds__(256) void k_csum(const float* __restrict__ gcount,
                                              float* __restrict__ cfin, int nb) {
    int k = blockIdx.x * 256 + threadIdx.x;
    if (k >= KC) return;
    float s = 0.f;
    for (int b = 0; b < nb; ++b) s += gcount[(size_t)b * KC + k];
    cfin[k] = s;
}

// ---------------- K3b: reduce sum partials + EMA update -> embedding_new -----
// usage==0 clusters never appear in encoding_index, so flat[r] path is dead.
__global__ __launch_bounds__(256) void k_embnew(
    const float* __restrict__ gpart, const float* __restrict__ cfin,
    const float* __restrict__ cnt_in, const float* __restrict__ sum_embed,
    float* __restrict__ embnew, int P) {
    int i = blockIdx.x * 256 + threadIdx.x;  // < KC*D
    int k = i >> 6;
    float s = 0.f;
    for (int p = 0; p < P; ++p) s += gpart[(size_t)p * (KC * D) + i];
    float c = cfin[k];
    float c0 = cnt_in[k];
    float cn = c0 + EMA_A * (c - c0);
    float se0 = sum_embed[i];
    float se = se0 + EMA_A * (s - se0);
    bool used = (cn >= 1.0f);
    embnew[i] = used ? (se / cn) : 0.0f;  // unused entries are never gathered
}

// ---------------- K4: gather out[n][:] = embnew[idx[n]][:] ----------------
__global__ __launch_bounds__(256) void k_gather(const int* __restrict__ idx,
                                                const float* __restrict__ embnew,
                                                float* __restrict__ out, int N) {
    int g = blockIdx.x * 256 + threadIdx.x;  // N * 16 work items
    int row = g >> 4, q = g & 15;
    if (row >= N) return;
    int k = idx[row];
    const float4* e4 = (const float4*)embnew;
    ((float4*)out)[(size_t)row * (D / 4) + q] = e4[k * (D / 4) + q];
}

extern "C" void kernel_launch(void* const* d_in, const int* in_sizes, int n_in,
                              void* d_out, int out_size, void* d_ws, size_t ws_size,
                              hipStream_t stream) {
    const float* x = (const float*)d_in[0];
    const float* emb = (const float*)d_in[1];
    const float* cnt = (const float*)d_in[2];
    const float* sum_embed = (const float*)d_in[3];
    float* out = (float*)d_out;
    int N = in_sizes[0] / D;  // 262144

    char* w = (char*)d_ws;
    size_t off = 0;
    int* idx = (int*)(w + off);        off += (size_t)N * 4;
    float* ee = (float*)(w + off);     off += (size_t)KC * 4;
    float* cfin = (float*)(w + off);   off += (size_t)KC * 4;
    float* embnew = (float*)(w + off); off += (size_t)KC * D * 4;
    float* embP = (float*)(w + off);   off += (size_t)KC * D * 4;
    int cblocks = (N + CROWS - 1) / CROWS;
    float* gcount = (float*)(w + off); off += (size_t)cblocks * KC * 4;
    size_t fixed = off;
    size_t perP = (size_t)KC * D * 4;
    int P = 256;
    if (ws_size > fixed) {
        size_t maxP = (ws_size - fixed) / perP;
        if ((size_t)P > maxP) P = (int)maxP;
    }
    if (P < 1) P = 1;
    float* gpart = (float*)(w + off);

    k_prep<<<(KC + 255) / 256, 256, 0, stream>>>(emb, embP, ee);
    k_assign<<<N / 256, 256, 0, stream>>>(x, embP, ee, idx);
    k_count<<<cblocks, 256, 0, stream>>>(idx, gcount, N);
    k_segsum<<<P, 256, 0, stream>>>(x, idx, gpart, N, P);
    k_csum<<<(KC + 255) / 256, 256, 0, stream>>>(gcount, cfin, cblocks);
    k_embnew<<<(KC * D) / 256, 256, 0, stream>>>(gpart, cfin, cnt, sum_embed, embnew, P);
    k_gather<<<((size_t)N * (D / 4) + 255) / 256, 256, 0, stream>>>(idx, embnew, out, N);
}

// Round 3
// 511.239 us; speedup vs baseline: 1.2248x; 1.2248x over previous
//
#include <hip/hip_runtime.h>

#define D 64
#define KC 512        // number of codebook entries
#define EMA_A 0.01f   // 1 - EMA_DECAY
#define SCHUNK 1024   // rows per segsum chunk
#define NCHUNK 256    // N / SCHUNK
#define ABLK 1024     // k_assign grid (N/256)

typedef float v4f __attribute__((ext_vector_type(4)));

// ---- K0: ee[k] = ||emb_k||^2 ----
__global__ __launch_bounds__(256) void k_prep(const float* __restrict__ emb,
                                              float* __restrict__ ee) {
    int k = blockIdx.x * 256 + threadIdx.x;
    if (k >= KC) return;
    float s = 0.f;
#pragma unroll
    for (int d = 0; d < D; ++d) { float e = emb[k * D + d]; s = fmaf(e, e, s); }
    ee[k] = s;
}

// ---------------- K1: per-row argmin over 512 clusters + count histogram ----
// x row in 16 NAMED v4f values (no alloca -> nothing to spill). emb read
// wave-uniformly (s_load). v4f mul-add -> v_pk_fma_f32 (fp-contract=fast).
__global__ __launch_bounds__(256, 3) void k_assign(
    const float* __restrict__ x, const v4f* __restrict__ e4,
    const float* __restrict__ ee, int* __restrict__ idx,
    float* __restrict__ gcount) {
    __shared__ int hist[KC];
    int tid = threadIdx.x;
    for (int i = tid; i < KC; i += 256) hist[i] = 0;
    __syncthreads();

    int n = blockIdx.x * 256 + tid;
    const v4f* xp = (const v4f*)(x + (size_t)n * D);
    v4f X0 = xp[0],  X1 = xp[1],  X2 = xp[2],  X3 = xp[3];
    v4f X4 = xp[4],  X5 = xp[5],  X6 = xp[6],  X7 = xp[7];
    v4f X8 = xp[8],  X9 = xp[9],  X10 = xp[10], X11 = xp[11];
    v4f X12 = xp[12], X13 = xp[13], X14 = xp[14], X15 = xp[15];

    v4f sq = X0 * X0;
    sq += X1 * X1;   sq += X2 * X2;   sq += X3 * X3;
    sq += X4 * X4;   sq += X5 * X5;   sq += X6 * X6;
    sq += X7 * X7;   sq += X8 * X8;   sq += X9 * X9;
    sq += X10 * X10; sq += X11 * X11; sq += X12 * X12;
    sq += X13 * X13; sq += X14 * X14; sq += X15 * X15;
    float xx = (sq.x + sq.y) + (sq.z + sq.w);

    float best = 3.4e38f;
    int bi = 0;
    for (int k0 = 0; k0 < KC; k0 += 8) {
        const v4f* e = e4 + (size_t)k0 * (D / 4);
#define DOT8(J, AJ)                                                       \
        v4f AJ;                                                           \
        { const v4f* ej = e + (size_t)(J) * (D / 4);                      \
          AJ  = X0 * ej[0];   AJ += X1 * ej[1];                           \
          AJ += X2 * ej[2];   AJ += X3 * ej[3];                           \
          AJ += X4 * ej[4];   AJ += X5 * ej[5];                           \
          AJ += X6 * ej[6];   AJ += X7 * ej[7];                           \
          AJ += X8 * ej[8];   AJ += X9 * ej[9];                           \
          AJ += X10 * ej[10]; AJ += X11 * ej[11];                         \
          AJ += X12 * ej[12]; AJ += X13 * ej[13];                         \
          AJ += X14 * ej[14]; AJ += X15 * ej[15]; }
        DOT8(0, A0) DOT8(1, A1) DOT8(2, A2) DOT8(3, A3)
        DOT8(4, A4) DOT8(5, A5) DOT8(6, A6) DOT8(7, A7)
#undef DOT8
#define FIN(J, AJ)                                                        \
        { float s = (AJ.x + AJ.y) + (AJ.z + AJ.w);                        \
          float dd = fmaf(-2.0f, s, xx + ee[k0 + (J)]);                   \
          if (dd < best) { best = dd; bi = k0 + (J); } }  /* first-min */
        FIN(0, A0) FIN(1, A1) FIN(2, A2) FIN(3, A3)
        FIN(4, A4) FIN(5, A5) FIN(6, A6) FIN(7, A7)
#undef FIN
    }
    idx[n] = bi;
    atomicAdd(&hist[bi], 1);
    __syncthreads();
    for (int i = tid; i < KC; i += 256)
        gcount[(size_t)blockIdx.x * KC + i] = (float)hist[i];
}

// ---- K2: LDS-privatized segment sums; k-halves split across BLOCKS ----
// grid = NCHUNK*2 (chunk, half). 64 KB static LDS -> 2 blocks/CU, 16 waves.
__global__ __launch_bounds__(512) void k_segsum(
    const float* __restrict__ x, const int* __restrict__ idx,
    float* __restrict__ gpart, int N) {
    __shared__ float part[256 * D];  // 64 KB exactly
    int tid = threadIdx.x;
    int chunk = blockIdx.x >> 1;
    int half = blockIdx.x & 1;
    int base = chunk * SCHUNK;
    int end = base + SCHUNK; if (end > N) end = N;
    for (int i = tid; i < 256 * D; i += 512) part[i] = 0.f;
    __syncthreads();
    for (int r = base + tid; r < end; r += 512) {
        int k = idx[r];
        if ((k >> 8) == half) {
            int kl = k & 255;
            const float4* p = (const float4*)(x + (size_t)r * D);
#pragma unroll
            for (int i = 0; i < D / 4; ++i) {
                float4 v = p[i];
                int d = 4 * i;
                atomicAdd(&part[kl * D + ((d + 0 + kl) & 63)], v.x);
                atomicAdd(&part[kl * D + ((d + 1 + kl) & 63)], v.y);
                atomicAdd(&part[kl * D + ((d + 2 + kl) & 63)], v.z);
                atomicAdd(&part[kl * D + ((d + 3 + kl) & 63)], v.w);
            }
        }
    }
    __syncthreads();
    // gpart layout: [chunk][k][d], k = half*256 + kl
    size_t ob = (size_t)chunk * (KC * D) + (size_t)half * (256 * D);
    for (int i = tid; i < 256 * D; i += 512) {
        int kl = i >> 6, d = i & 63;
        gpart[ob + i] = part[kl * D + ((d + kl) & 63)];
    }
}

// ---- K3a: stage-1 reduce of gpart over chunks: 4 groups of 64 ----
__global__ __launch_bounds__(256) void k_sumred(const float* __restrict__ gpart,
                                                float* __restrict__ spart) {
    int b = blockIdx.x;           // 512 blocks: g = b>>7 (0..3), islice = b&127
    int g = b >> 7;
    int i = (b & 127) * 256 + threadIdx.x;   // i < KC*D
    float s = 0.f;
    for (int c = g * 64; c < g * 64 + 64; ++c)
        s += gpart[(size_t)c * (KC * D) + i];
    spart[(size_t)g * (KC * D) + i] = s;
}

// ---- K3b: reduce gcount over ABLK partials: 8 groups of 128 ----
__global__ __launch_bounds__(256) void k_cred(const float* __restrict__ gcount,
                                              float* __restrict__ cpart) {
    int gid = blockIdx.x * 256 + threadIdx.x;  // 16 blocks -> 4096 = 8*512
    int g = gid >> 9;
    int k = gid & 511;
    float s = 0.f;
    for (int b = g * 128; b < g * 128 + 128; ++b)
        s += gcount[(size_t)b * KC + k];
    cpart[gid] = s;
}

// ---- K4: finish reductions + EMA update -> embedding_new ----
// usage==0 clusters never appear in encoding_index -> flat[r] path is dead.
__global__ __launch_bounds__(256) void k_embnew(
    const float* __restrict__ spart, const float* __restrict__ cpart,
    const float* __restrict__ cnt_in, const float* __restrict__ sum_embed,
    float* __restrict__ embnew) {
    int i = blockIdx.x * 256 + threadIdx.x;  // < KC*D
    int k = i >> 6;
    float s = spart[i] + spart[(size_t)1 * (KC * D) + i] +
              spart[(size_t)2 * (KC * D) + i] + spart[(size_t)3 * (KC * D) + i];
    float c = 0.f;
#pragma unroll
    for (int g = 0; g < 8; ++g) c += cpart[g * KC + k];
    float c0 = cnt_in[k];
    float cn = c0 + EMA_A * (c - c0);
    float se0 = sum_embed[i];
    float se = se0 + EMA_A * (s - se0);
    embnew[i] = (cn >= 1.0f) ? (se / cn) : 0.0f;
}

// ---- K5: gather out[n][:] = embnew[idx[n]][:] ----
__global__ __launch_bounds__(256) void k_gather(const int* __restrict__ idx,
                                                const float* __restrict__ embnew,
                                                float* __restrict__ out, int N) {
    int g = blockIdx.x * 256 + threadIdx.x;  // N * 16 work items
    int row = g >> 4, q = g & 15;
    if (row >= N) return;
    int k = idx[row];
    const float4* e4 = (const float4*)embnew;
    ((float4*)out)[(size_t)row * (D / 4) + q] = e4[k * (D / 4) + q];
}

extern "C" void kernel_launch(void* const* d_in, const int* in_sizes, int n_in,
                              void* d_out, int out_size, void* d_ws, size_t ws_size,
                              hipStream_t stream) {
    const float* x = (const float*)d_in[0];
    const float* emb = (const float*)d_in[1];
    const float* cnt = (const float*)d_in[2];
    const float* sum_embed = (const float*)d_in[3];
    float* out = (float*)d_out;
    int N = in_sizes[0] / D;  // 262144

    char* w = (char*)d_ws;
    size_t off = 0;
    int* idx = (int*)(w + off);        off += (size_t)N * 4;
    float* ee = (float*)(w + off);     off += (size_t)KC * 4;
    float* embnew = (float*)(w + off); off += (size_t)KC * D * 4;
    float* gcount = (float*)(w + off); off += (size_t)ABLK * KC * 4;
    float* cpart = (float*)(w + off);  off += (size_t)8 * KC * 4;
    float* spart = (float*)(w + off);  off += (size_t)4 * KC * D * 4;
    float* gpart = (float*)(w + off);  off += (size_t)NCHUNK * KC * D * 4;

    k_prep<<<(KC + 255) / 256, 256, 0, stream>>>(emb, ee);
    k_assign<<<N / 256, 256, 0, stream>>>(x, (const v4f*)emb, ee, idx, gcount);
    k_segsum<<<NCHUNK * 2, 512, 0, stream>>>(x, idx, gpart, N);
    k_sumred<<<512, 256, 0, stream>>>(gpart, spart);
    k_cred<<<16, 256, 0, stream>>>(gcount, cpart);
    k_embnew<<<(KC * D) / 256, 256, 0, stream>>>(spart, cpart, cnt, sum_embed, embnew);
    k_gather<<<((size_t)N * (D / 4) + 255) / 256, 256, 0, stream>>>(idx, embnew, out, N);
}

// Round 4
// 509.057 us; speedup vs baseline: 1.2301x; 1.0043x over previous
//
#include <hip/hip_runtime.h>

#define D 64
#define KC 512        // number of codebook entries
#define EMA_A 0.01f   // 1 - EMA_DECAY
#define SCHUNK 1024   // rows per segsum chunk
#define NCHUNK 256    // N / SCHUNK
#define FBLK 1024     // k_finish grid (N/256)

typedef float v2f __attribute__((ext_vector_type(2)));
typedef float v4f __attribute__((ext_vector_type(4)));

// ---- K0: ee[k] = ||emb_k||^2 ----
__global__ __launch_bounds__(256) void k_prep(const float* __restrict__ emb,
                                              float* __restrict__ ee) {
    int k = blockIdx.x * 256 + threadIdx.x;
    if (k >= KC) return;
    float s = 0.f;
#pragma unroll
    for (int d = 0; d < D; ++d) { float e = emb[k * D + d]; s = fmaf(e, e, s); }
    ee[k] = s;
}

// ---- K1: LDS-tiled GEMM partial-argmin ----
// Block 256 thr (16x16). Tile 128 rows x 64 clusters. x-tile 32KB + e-tile
// 16KB, XOR-swizzled so every ds op is a conflict-free b128. Per-thread 8x4
// tile, v2f accumulators over k-pairs -> v_pk_fma_f32. xx (row-constant)
// dropped: argmin(ee - 2 x.e) == argmin(dist).
__global__ __launch_bounds__(256, 3) void k_assign(
    const float* __restrict__ x, const float* __restrict__ emb,
    const float* __restrict__ ee, float2* __restrict__ pmin, int N) {
    __shared__ float xs[128 * 64];  // 32 KB, swizzled [row][sw(d4)]
    __shared__ float es[64 * 64];   // 16 KB, swizzled [col][sw(d4)]
    int tid = threadIdx.x;
    int cb = blockIdx.x & 7;   // 8 column blocks of 64 clusters
    int rb = blockIdx.x >> 3;
    int n0 = rb * 128;

    // stage x-tile (coalesced float4), swizzle sw = (d4 + 2*(r&7) + (r>>3)) & 15
    const float4* xg = (const float4*)(x + (size_t)n0 * D);
#pragma unroll
    for (int p = 0; p < 8; ++p) {
        int flat = p * 256 + tid;
        int row = flat >> 4, d4 = flat & 15;
        float4 v = xg[flat];
        int sw = (d4 + 2 * (row & 7) + (row >> 3)) & 15;
        ((v4f*)xs)[row * 16 + sw] = (v4f){v.x, v.y, v.z, v.w};
    }
    // stage e-tile, swizzle sw = (d4 + 4*(c&3) + (c>>2)) & 15
    const float4* eg = (const float4*)(emb + (size_t)cb * 64 * D);
#pragma unroll
    for (int p = 0; p < 4; ++p) {
        int flat = p * 256 + tid;
        int c = flat >> 4, d4 = flat & 15;
        float4 v = eg[flat];
        int sw = (d4 + 4 * (c & 3) + (c >> 2)) & 15;
        ((v4f*)es)[c * 16 + sw] = (v4f){v.x, v.y, v.z, v.w};
    }
    __syncthreads();

    int ty = tid >> 4, tx = tid & 15;  // rows ty*8.., cols tx*4..
    v2f acc[8][4];
#pragma unroll
    for (int i = 0; i < 8; ++i)
#pragma unroll
        for (int j = 0; j < 4; ++j) acc[i][j] = (v2f){0.f, 0.f};

    for (int dq = 0; dq < 16; ++dq) {  // 4 k-steps per iteration
        v4f a4[8], b4[4];
#pragma unroll
        for (int i = 0; i < 8; ++i) {
            int r = ty * 8 + i;
            int sw = (dq + 2 * (r & 7) + (r >> 3)) & 15;
            a4[i] = ((const v4f*)xs)[r * 16 + sw];
        }
#pragma unroll
        for (int j = 0; j < 4; ++j) {
            int c = tx * 4 + j;
            int sw = (dq + 4 * (c & 3) + (c >> 2)) & 15;
            b4[j] = ((const v4f*)es)[c * 16 + sw];
        }
#pragma unroll
        for (int i = 0; i < 8; ++i) {
            v2f a0 = __builtin_shufflevector(a4[i], a4[i], 0, 1);
            v2f a1 = __builtin_shufflevector(a4[i], a4[i], 2, 3);
#pragma unroll
            for (int j = 0; j < 4; ++j) {
                v2f b0 = __builtin_shufflevector(b4[j], b4[j], 0, 1);
                v2f b1 = __builtin_shufflevector(b4[j], b4[j], 2, 3);
                acc[i][j] += a0 * b0;
                acc[i][j] += a1 * b1;
            }
        }
    }

    // epilogue: per-row lexicographic (dist, idx) partial min over 4 cols
    float eej[4];
#pragma unroll
    for (int j = 0; j < 4; ++j) eej[j] = ee[cb * 64 + tx * 4 + j];
    __syncthreads();                 // xs reuse as reduction buffer
    float2* red = (float2*)xs;       // red[row][17] (pad 17 kills conflicts)
#pragma unroll
    for (int i = 0; i < 8; ++i) {
        float bd = 3.4e38f; int bi = 0x7fffffff;
#pragma unroll
        for (int j = 0; j < 4; ++j) {
            float dot = acc[i][j].x + acc[i][j].y;
            float dd = fmaf(-2.0f, dot, eej[j]);
            int ci = cb * 64 + tx * 4 + j;
            if (dd < bd || (dd == bd && ci < bi)) { bd = dd; bi = ci; }
        }
        red[(ty * 8 + i) * 17 + tx] = make_float2(bd, __int_as_float(bi));
    }
    __syncthreads();
    if (tid < 128) {
        float bd = 3.4e38f; int bi = 0x7fffffff;
#pragma unroll
        for (int t = 0; t < 16; ++t) {
            float2 e = red[tid * 17 + t];
            int ci = __float_as_int(e.y);
            if (e.x < bd || (e.x == bd && ci < bi)) { bd = e.x; bi = ci; }
        }
        pmin[(size_t)cb * N + n0 + tid] = make_float2(bd, __int_as_float(bi));
    }
}

// ---- K1b: reduce 8 column-block partials -> idx + per-block histogram ----
__global__ __launch_bounds__(256) void k_finish(
    const float2* __restrict__ pmin, int* __restrict__ idx,
    float* __restrict__ gcount, int N) {
    __shared__ int hist[KC];
    int tid = threadIdx.x;
    for (int i = tid; i < KC; i += 256) hist[i] = 0;
    __syncthreads();
    int n = blockIdx.x * 256 + tid;
    float bd = 3.4e38f; int bi = 0x7fffffff;
#pragma unroll
    for (int c = 0; c < 8; ++c) {
        float2 e = pmin[(size_t)c * N + n];
        int ci = __float_as_int(e.y);
        if (e.x < bd || (e.x == bd && ci < bi)) { bd = e.x; bi = ci; }
    }
    idx[n] = bi;
    atomicAdd(&hist[bi], 1);
    __syncthreads();
    for (int i = tid; i < KC; i += 256)
        gcount[(size_t)blockIdx.x * KC + i] = (float)hist[i];
}

// ---- K2: LDS-privatized segment sums; k-halves split across BLOCKS ----
__global__ __launch_bounds__(512) void k_segsum(
    const float* __restrict__ x, const int* __restrict__ idx,
    float* __restrict__ gpart, int N) {
    __shared__ float part[256 * D];  // 64 KB exactly
    int tid = threadIdx.x;
    int chunk = blockIdx.x >> 1;
    int half = blockIdx.x & 1;
    int base = chunk * SCHUNK;
    int end = base + SCHUNK; if (end > N) end = N;
    for (int i = tid; i < 256 * D; i += 512) part[i] = 0.f;
    __syncthreads();
    for (int r = base + tid; r < end; r += 512) {
        int k = idx[r];
        if ((k >> 8) == half) {
            int kl = k & 255;
            const float4* p = (const float4*)(x + (size_t)r * D);
#pragma unroll
            for (int i = 0; i < D / 4; ++i) {
                float4 v = p[i];
                int d = 4 * i;
                atomicAdd(&part[kl * D + ((d + 0 + kl) & 63)], v.x);
                atomicAdd(&part[kl * D + ((d + 1 + kl) & 63)], v.y);
                atomicAdd(&part[kl * D + ((d + 2 + kl) & 63)], v.z);
                atomicAdd(&part[kl * D + ((d + 3 + kl) & 63)], v.w);
            }
        }
    }
    __syncthreads();
    size_t ob = (size_t)chunk * (KC * D) + (size_t)half * (256 * D);
    for (int i = tid; i < 256 * D; i += 512) {
        int kl = i >> 6, d = i & 63;
        gpart[ob + i] = part[kl * D + ((d + kl) & 63)];
    }
}

// ---- K3a: stage-1 reduce of gpart over chunks: 4 groups of 64 ----
__global__ __launch_bounds__(256) void k_sumred(const float* __restrict__ gpart,
                                                float* __restrict__ spart) {
    int b = blockIdx.x;
    int g = b >> 7;
    int i = (b & 127) * 256 + threadIdx.x;
    float s = 0.f;
    for (int c = g * 64; c < g * 64 + 64; ++c)
        s += gpart[(size_t)c * (KC * D) + i];
    spart[(size_t)g * (KC * D) + i] = s;
}

// ---- K3b: reduce gcount over FBLK partials: 8 groups of 128 ----
__global__ __launch_bounds__(256) void k_cred(const float* __restrict__ gcount,
                                              float* __restrict__ cpart) {
    int gid = blockIdx.x * 256 + threadIdx.x;
    int g = gid >> 9;
    int k = gid & 511;
    float s = 0.f;
    for (int b = g * 128; b < g * 128 + 128; ++b)
        s += gcount[(size_t)b * KC + k];
    cpart[gid] = s;
}

// ---- K4: finish reductions + EMA update -> embedding_new ----
// usage==0 clusters never appear in encoding_index -> flat[r] path is dead.
__global__ __launch_bounds__(256) void k_embnew(
    const float* __restrict__ spart, const float* __restrict__ cpart,
    const float* __restrict__ cnt_in, const float* __restrict__ sum_embed,
    float* __restrict__ embnew) {
    int i = blockIdx.x * 256 + threadIdx.x;
    int k = i >> 6;
    float s = spart[i] + spart[(size_t)1 * (KC * D) + i] +
              spart[(size_t)2 * (KC * D) + i] + spart[(size_t)3 * (KC * D) + i];
    float c = 0.f;
#pragma unroll
    for (int g = 0; g < 8; ++g) c += cpart[g * KC + k];
    float c0 = cnt_in[k];
    float cn = c0 + EMA_A * (c - c0);
    float se0 = sum_embed[i];
    float se = se0 + EMA_A * (s - se0);
    embnew[i] = (cn >= 1.0f) ? (se / cn) : 0.0f;
}

// ---- K5: gather out[n][:] = embnew[idx[n]][:] ----
__global__ __launch_bounds__(256) void k_gather(const int* __restrict__ idx,
                                                const float* __restrict__ embnew,
                                                float* __restrict__ out, int N) {
    int g = blockIdx.x * 256 + threadIdx.x;
    int row = g >> 4, q = g & 15;
    if (row >= N) return;
    int k = idx[row];
    const float4* e4 = (const float4*)embnew;
    ((float4*)out)[(size_t)row * (D / 4) + q] = e4[k * (D / 4) + q];
}

extern "C" void kernel_launch(void* const* d_in, const int* in_sizes, int n_in,
                              void* d_out, int out_size, void* d_ws, size_t ws_size,
                              hipStream_t stream) {
    const float* x = (const float*)d_in[0];
    const float* emb = (const float*)d_in[1];
    const float* cnt = (const float*)d_in[2];
    const float* sum_embed = (const float*)d_in[3];
    float* out = (float*)d_out;
    int N = in_sizes[0] / D;  // 262144

    char* w = (char*)d_ws;
    size_t off = 0;
    int* idx = (int*)(w + off);        off += (size_t)N * 4;
    float* ee = (float*)(w + off);     off += (size_t)KC * 4;
    float* embnew = (float*)(w + off); off += (size_t)KC * D * 4;
    float2* pmin = (float2*)(w + off); off += (size_t)8 * N * 8;
    float* gcount = (float*)(w + off); off += (size_t)FBLK * KC * 4;
    float* cpart = (float*)(w + off);  off += (size_t)8 * KC * 4;
    float* spart = (float*)(w + off);  off += (size_t)4 * KC * D * 4;
    float* gpart = (float*)(w + off);  off += (size_t)NCHUNK * KC * D * 4;

    k_prep<<<(KC + 255) / 256, 256, 0, stream>>>(emb, ee);
    k_assign<<<(N / 128) * 8, 256, 0, stream>>>(x, emb, ee, pmin, N);
    k_finish<<<N / 256, 256, 0, stream>>>(pmin, idx, gcount, N);
    k_segsum<<<NCHUNK * 2, 512, 0, stream>>>(x, idx, gpart, N);
    k_sumred<<<512, 256, 0, stream>>>(gpart, spart);
    k_cred<<<16, 256, 0, stream>>>(gcount, cpart);
    k_embnew<<<(KC * D) / 256, 256, 0, stream>>>(spart, cpart, cnt, sum_embed, embnew);
    k_gather<<<((size_t)N * (D / 4) + 255) / 256, 256, 0, stream>>>(idx, embnew, out, N);
}

// Round 5
// 419.757 us; speedup vs baseline: 1.4918x; 1.2127x over previous
//
#include <hip/hip_runtime.h>

#define D 64
#define KC 512
#define EMA_A 0.01f
#define SCHUNK 1024   // rows per segsum chunk
#define NCHUNK 256    // N / SCHUNK
#define BAND 0.03125f // recheck band in he-units (~24x worst-case approx error)

typedef float f32x4 __attribute__((ext_vector_type(4)));
typedef float v4f __attribute__((ext_vector_type(4)));
typedef short s8v __attribute__((ext_vector_type(8)));   // 8 bf16 as shorts
typedef short s4v __attribute__((ext_vector_type(4)));

__device__ inline unsigned short bf16_rne(float f) {
    unsigned u = __float_as_uint(f);
    return (unsigned short)((u + 0x7fffu + ((u >> 16) & 1u)) >> 16);
}
__device__ inline float bf16_f(unsigned short h) {
    return __uint_as_float(((unsigned)h) << 16);
}

// ---- K0: he[k] = 0.5*||emb_k||^2 (argmin(he - dot) == argmin(dist)) ----
__global__ __launch_bounds__(256) void k_prep(const float* __restrict__ emb,
                                              float* __restrict__ he) {
    int k = blockIdx.x * 256 + threadIdx.x;
    if (k >= KC) return;
    float s = 0.f;
#pragma unroll
    for (int d = 0; d < D; ++d) { float e = emb[k * D + d]; s = fmaf(e, e, s); }
    he[k] = 0.5f * s;
}

// ---- K1: MFMA split-bf16 argmin. Block=256thr(4 waves), 128 rows x all 512
// cols. A(x) hi/lo 32KB LDS, B(emb) hi/lo staged 64-col chunks (16KB) ->
// 48KB total -> 3 blocks/CU. dot = hh+hl+lh (6 mfma into one fp32 acc).
// XOR-swizzled 16B blocks: all ds ops conflict-free b128/b64.
__global__ __launch_bounds__(256, 3) void k_assign(
    const float* __restrict__ x, const float* __restrict__ emb,
    const float* __restrict__ he, int* __restrict__ idx,
    float* __restrict__ gap) {
    __shared__ __align__(16) short Ahi[128 * 64];
    __shared__ __align__(16) short Alo[128 * 64];
    __shared__ __align__(16) short Bhi[64 * 64];
    __shared__ __align__(16) short Blo[64 * 64];
    int tid = threadIdx.x;
    int lane = tid & 63, w = tid >> 6, q = lane >> 4, c16 = lane & 15;
    size_t R0 = (size_t)blockIdx.x * 128;

    // stage A: fp32 x tile -> hi/lo bf16, swizzle block kb^=(row&7)
    const float4* xg = (const float4*)(x + R0 * D);
#pragma unroll
    for (int p = 0; p < 8; ++p) {
        int flat = p * 256 + tid;
        int row = flat >> 4, kq = flat & 15;
        float4 v = xg[flat];
        unsigned short h0 = bf16_rne(v.x), h1 = bf16_rne(v.y);
        unsigned short h2 = bf16_rne(v.z), h3 = bf16_rne(v.w);
        s4v hv = {(short)h0, (short)h1, (short)h2, (short)h3};
        s4v lv = {(short)bf16_rne(v.x - bf16_f(h0)),
                  (short)bf16_rne(v.y - bf16_f(h1)),
                  (short)bf16_rne(v.z - bf16_f(h2)),
                  (short)bf16_rne(v.w - bf16_f(h3))};
        int si = row * 64 + (((kq >> 1) ^ (row & 7)) * 8) + (kq & 1) * 4;
        *(s4v*)(&Ahi[si]) = hv;
        *(s4v*)(&Alo[si]) = lv;
    }
    __syncthreads();

    // A fragments held in regs for the whole kernel (8 frags = 32 VGPR)
    s8v ah[2][2], al[2][2];
#pragma unroll
    for (int rt = 0; rt < 2; ++rt)
#pragma unroll
        for (int ks = 0; ks < 2; ++ks) {
            int row = w * 32 + rt * 16 + c16;
            int kb = (ks * 4 + q) ^ (row & 7);
            ah[rt][ks] = *(const s8v*)(&Ahi[row * 64 + kb * 8]);
            al[rt][ks] = *(const s8v*)(&Alo[row * 64 + kb * 8]);
        }

    float m1[8], m2[8]; int i1[8];
#pragma unroll
    for (int e = 0; e < 8; ++e) { m1[e] = 3.4e38f; m2[e] = 3.4e38f; i1[e] = 0; }

    for (int c8 = 0; c8 < 8; ++c8) {
        if (c8) __syncthreads();
        const float4* eg = (const float4*)(emb + (size_t)c8 * 64 * D);
#pragma unroll
        for (int p = 0; p < 4; ++p) {
            int flat = p * 256 + tid;
            int c = flat >> 4, kq = flat & 15;
            float4 v = eg[flat];
            unsigned short h0 = bf16_rne(v.x), h1 = bf16_rne(v.y);
            unsigned short h2 = bf16_rne(v.z), h3 = bf16_rne(v.w);
            s4v hv = {(short)h0, (short)h1, (short)h2, (short)h3};
            s4v lv = {(short)bf16_rne(v.x - bf16_f(h0)),
                      (short)bf16_rne(v.y - bf16_f(h1)),
                      (short)bf16_rne(v.z - bf16_f(h2)),
                      (short)bf16_rne(v.w - bf16_f(h3))};
            int si = c * 64 + (((kq >> 1) ^ (c & 7)) * 8) + (kq & 1) * 4;
            *(s4v*)(&Bhi[si]) = hv;
            *(s4v*)(&Blo[si]) = lv;
        }
        __syncthreads();
#pragma unroll
        for (int ct = 0; ct < 4; ++ct) {
            s8v bh[2], bl[2];
#pragma unroll
            for (int ks = 0; ks < 2; ++ks) {
                int c = ct * 16 + c16;
                int kb = (ks * 4 + q) ^ (c & 7);
                bh[ks] = *(const s8v*)(&Bhi[c * 64 + kb * 8]);
                bl[ks] = *(const s8v*)(&Blo[c * 64 + kb * 8]);
            }
            int cbase = c8 * 64 + ct * 16;
            float hec = he[cbase + c16];
            int ci = cbase + c16;
#pragma unroll
            for (int rt = 0; rt < 2; ++rt) {
                f32x4 acc = {0.f, 0.f, 0.f, 0.f};
                acc = __builtin_amdgcn_mfma_f32_16x16x32_bf16(ah[rt][0], bh[0], acc, 0, 0, 0);
                acc = __builtin_amdgcn_mfma_f32_16x16x32_bf16(ah[rt][1], bh[1], acc, 0, 0, 0);
                acc = __builtin_amdgcn_mfma_f32_16x16x32_bf16(ah[rt][0], bl[0], acc, 0, 0, 0);
                acc = __builtin_amdgcn_mfma_f32_16x16x32_bf16(ah[rt][1], bl[1], acc, 0, 0, 0);
                acc = __builtin_amdgcn_mfma_f32_16x16x32_bf16(al[rt][0], bh[0], acc, 0, 0, 0);
                acc = __builtin_amdgcn_mfma_f32_16x16x32_bf16(al[rt][1], bh[1], acc, 0, 0, 0);
#pragma unroll
                for (int r = 0; r < 4; ++r) {
                    float d = hec - acc[r];
                    int e = rt * 4 + r;
                    m2[e] = fminf(m2[e], fmaxf(d, m1[e]));  // before m1 update
                    bool lt = d < m1[e];                    // strict: first-min
                    i1[e] = lt ? ci : i1[e];
                    m1[e] = fminf(m1[e], d);
                }
            }
        }
    }
    // reduce (m1,i1,m2) across the 16 lanes of each quad group
#pragma unroll
    for (int m = 1; m < 16; m <<= 1) {
#pragma unroll
        for (int e = 0; e < 8; ++e) {
            float om1 = __shfl_xor(m1[e], m);
            float om2 = __shfl_xor(m2[e], m);
            int oi = __shfl_xor(i1[e], m);
            float nm2 = fminf(fminf(m2[e], om2), fmaxf(m1[e], om1));
            bool take = (om1 < m1[e]) || (om1 == m1[e] && oi < i1[e]);
            i1[e] = take ? oi : i1[e];
            m1[e] = fminf(m1[e], om1);
            m2[e] = nm2;
        }
    }
    if (c16 == 0) {
#pragma unroll
        for (int e = 0; e < 8; ++e) {
            int row = (int)R0 + w * 32 + (e >> 2) * 16 + q * 4 + (e & 3);
            idx[row] = i1[e];
            gap[row] = m2[e] - m1[e];
        }
    }
}

// ---- K1b: exact fp32 rescan for rows with approx gap < BAND (~1-3%) ----
__global__ __launch_bounds__(256) void k_recheck(
    const float* __restrict__ x, const float* __restrict__ emb,
    const float* __restrict__ he, const float* __restrict__ gap,
    int* __restrict__ idx) {
    int tid = threadIdx.x;
    int lane = tid & 63, w = tid >> 6;
    int base = (blockIdx.x * 4 + w) * 64;
    float g = gap[base + lane];
    unsigned long long bal = __ballot(g < BAND);
    while (bal) {
        int b = __ffsll((unsigned long long)bal) - 1;
        bal &= bal - 1;
        int row = base + b;
        const v4f* xr = (const v4f*)(x + (size_t)row * D);
        v4f X[16];
#pragma unroll
        for (int i = 0; i < 16; ++i) X[i] = xr[i];
        float bd = 3.4e38f; int bi = 0x7fffffff;
#pragma unroll
        for (int j = 0; j < 8; ++j) {
            int c = j * 64 + lane;
            const v4f* er = (const v4f*)(emb + (size_t)c * D);
            v4f s = X[0] * er[0];
#pragma unroll
            for (int i = 1; i < 16; ++i) s += X[i] * er[i];
            float dot = (s.x + s.y) + (s.z + s.w);
            float d = he[c] - dot;
            if (d < bd) { bd = d; bi = c; }  // c ascending per lane
        }
#pragma unroll
        for (int m = 1; m < 64; m <<= 1) {
            float od = __shfl_xor(bd, m);
            int oi = __shfl_xor(bi, m);
            if (od < bd || (od == bd && oi < bi)) { bd = od; bi = oi; }
        }
        if (lane == 0) idx[row] = bi;
    }
}

// ---- K2a: per-block histogram ----
__global__ __launch_bounds__(256) void k_hist(const int* __restrict__ idx,
                                              float* __restrict__ gcount) {
    __shared__ int hist[KC];
    int tid = threadIdx.x;
    for (int i = tid; i < KC; i += 256) hist[i] = 0;
    __syncthreads();
    atomicAdd(&hist[idx[blockIdx.x * 256 + tid]], 1);
    __syncthreads();
    for (int i = tid; i < KC; i += 256)
        gcount[(size_t)blockIdx.x * KC + i] = (float)hist[i];
}

// ---- K2b: LDS-privatized segment sums; k-halves split across blocks ----
__global__ __launch_bounds__(512) void k_segsum(
    const float* __restrict__ x, const int* __restrict__ idx,
    float* __restrict__ gpart, int N) {
    __shared__ float part[256 * D];  // 64 KB
    int tid = threadIdx.x;
    int chunk = blockIdx.x >> 1;
    int half = blockIdx.x & 1;
    int base = chunk * SCHUNK;
    int end = base + SCHUNK; if (end > N) end = N;
    for (int i = tid; i < 256 * D; i += 512) part[i] = 0.f;
    __syncthreads();
    for (int r = base + tid; r < end; r += 512) {
        int k = idx[r];
        if ((k >> 8) == half) {
            int kl = k & 255;
            const float4* p = (const float4*)(x + (size_t)r * D);
#pragma unroll
            for (int i = 0; i < D / 4; ++i) {
                float4 v = p[i];
                int d = 4 * i;
                atomicAdd(&part[kl * D + ((d + 0 + kl) & 63)], v.x);
                atomicAdd(&part[kl * D + ((d + 1 + kl) & 63)], v.y);
                atomicAdd(&part[kl * D + ((d + 2 + kl) & 63)], v.z);
                atomicAdd(&part[kl * D + ((d + 3 + kl) & 63)], v.w);
            }
        }
    }
    __syncthreads();
    size_t ob = (size_t)chunk * (KC * D) + (size_t)half * (256 * D);
    for (int i = tid; i < 256 * D; i += 512) {
        int kl = i >> 6, d = i & 63;
        gpart[ob + i] = part[kl * D + ((d + kl) & 63)];
    }
}

// ---- K3a: stage-1 reduce of gpart over chunks: 4 groups of 64 ----
__global__ __launch_bounds__(256) void k_sumred(const float* __restrict__ gpart,
                                                float* __restrict__ spart) {
    int b = blockIdx.x;
    int g = b >> 7;
    int i = (b & 127) * 256 + threadIdx.x;
    float s = 0.f;
    for (int c = g * 64; c < g * 64 + 64; ++c)
        s += gpart[(size_t)c * (KC * D) + i];
    spart[(size_t)g * (KC * D) + i] = s;
}

// ---- K3b: reduce gcount over 1024 partials: 8 groups of 128 ----
__global__ __launch_bounds__(256) void k_cred(const float* __restrict__ gcount,
                                              float* __restrict__ cpart) {
    int gid = blockIdx.x * 256 + threadIdx.x;
    int g = gid >> 9;
    int k = gid & 511;
    float s = 0.f;
    for (int b = g * 128; b < g * 128 + 128; ++b)
        s += gcount[(size_t)b * KC + k];
    cpart[gid] = s;
}

// ---- K4: finish reductions + EMA -> embedding_new ----
// usage==0 clusters never appear in encoding_index -> flat[r] path is dead.
__global__ __launch_bounds__(256) void k_embnew(
    const float* __restrict__ spart, const float* __restrict__ cpart,
    const float* __restrict__ cnt_in, const float* __restrict__ sum_embed,
    float* __restrict__ embnew) {
    int i = blockIdx.x * 256 + threadIdx.x;
    int k = i >> 6;
    float s = spart[i] + spart[(size_t)1 * (KC * D) + i] +
              spart[(size_t)2 * (KC * D) + i] + spart[(size_t)3 * (KC * D) + i];
    float c = 0.f;
#pragma unroll
    for (int g = 0; g < 8; ++g) c += cpart[g * KC + k];
    float c0 = cnt_in[k];
    float cn = c0 + EMA_A * (c - c0);
    float se0 = sum_embed[i];
    float se = se0 + EMA_A * (s - se0);
    embnew[i] = (cn >= 1.0f) ? (se / cn) : 0.0f;
}

// ---- K5: gather ----
__global__ __launch_bounds__(256) void k_gather(const int* __restrict__ idx,
                                                const float* __restrict__ embnew,
                                                float* __restrict__ out, int N) {
    int g = blockIdx.x * 256 + threadIdx.x;
    int row = g >> 4, q = g & 15;
    if (row >= N) return;
    int k = idx[row];
    const float4* e4 = (const float4*)embnew;
    ((float4*)out)[(size_t)row * (D / 4) + q] = e4[k * (D / 4) + q];
}

extern "C" void kernel_launch(void* const* d_in, const int* in_sizes, int n_in,
                              void* d_out, int out_size, void* d_ws, size_t ws_size,
                              hipStream_t stream) {
    const float* x = (const float*)d_in[0];
    const float* emb = (const float*)d_in[1];
    const float* cnt = (const float*)d_in[2];
    const float* sum_embed = (const float*)d_in[3];
    float* out = (float*)d_out;
    int N = in_sizes[0] / D;  // 262144
    int hblk = N / 256;       // 1024

    char* w = (char*)d_ws;
    size_t off = 0;
    int* idx = (int*)(w + off);        off += (size_t)N * 4;
    float* gap = (float*)(w + off);    off += (size_t)N * 4;
    float* he = (float*)(w + off);     off += (size_t)KC * 4;
    float* embnew = (float*)(w + off); off += (size_t)KC * D * 4;
    float* gcount = (float*)(w + off); off += (size_t)hblk * KC * 4;
    float* cpart = (float*)(w + off);  off += (size_t)8 * KC * 4;
    float* spart = (float*)(w + off);  off += (size_t)4 * KC * D * 4;
    float* gpart = (float*)(w + off);  off += (size_t)NCHUNK * KC * D * 4;

    k_prep<<<(KC + 255) / 256, 256, 0, stream>>>(emb, he);
    k_assign<<<N / 128, 256, 0, stream>>>(x, emb, he, idx, gap);
    k_recheck<<<N / 256, 256, 0, stream>>>(x, emb, he, gap, idx);
    k_hist<<<hblk, 256, 0, stream>>>(idx, gcount);
    k_segsum<<<NCHUNK * 2, 512, 0, stream>>>(x, idx, gpart, N);
    k_sumred<<<512, 256, 0, stream>>>(gpart, spart);
    k_cred<<<16, 256, 0, stream>>>(gcount, cpart);
    k_embnew<<<(KC * D) / 256, 256, 0, stream>>>(spart, cpart, cnt, sum_embed, embnew);
    k_gather<<<((size_t)N * (D / 4)) / 256, 256, 0, stream>>>(idx, embnew, out, N);
}